// Round 11
// baseline (762.080 us; speedup 1.0000x reference)
//
#include <hip/hip_runtime.h>

#define DIM 32
#define NB  6
#define INV2PI 0.15915494309189535f

typedef _Float16 half8  __attribute__((ext_vector_type(8)));
typedef __fp16   fp16x2 __attribute__((ext_vector_type(2)));   // cvt_pkrtz result type
typedef int      int4v  __attribute__((ext_vector_type(4)));
typedef float    floatx16 __attribute__((ext_vector_type(16)));

// B-frag slot (s,h,j) holds raw channel P; C/D reg (r,h) holds raw channel Q.
__device__ __forceinline__ int Qmap(int p) { int r = p & 15, h = p >> 4; return 8*(r>>2) + 4*h + (r&3); }

#define MFMA(a, b, c) __builtin_amdgcn_mfma_f32_32x32x16_f16((a), (b), (c), 0, 0, 0)

// acc in revolution domain (weights prescaled by 1/2pi):
// raw v_sin then pairwise f16 pack via v_cvt_pkrtz (2 acts / instr).
// NOTE (measured R10): a union{half8; fp16x2[4]} here defeats SROA -> the
// union lives in scratch -> ~2 GB of scratch traffic. bit_cast stays in regs.
__device__ __forceinline__ void sincvt(const floatx16& acc, half8& b1, half8& b2) {
    int4v i1, i2;
    #pragma unroll
    for (int q = 0; q < 4; ++q) {
        i1[q] = __builtin_bit_cast(int,
                    __builtin_amdgcn_cvt_pkrtz(__builtin_amdgcn_sinf(acc[2*q]),
                                               __builtin_amdgcn_sinf(acc[2*q+1])));
        i2[q] = __builtin_bit_cast(int,
                    __builtin_amdgcn_cvt_pkrtz(__builtin_amdgcn_sinf(acc[8+2*q]),
                                               __builtin_amdgcn_sinf(acc[8+2*q+1])));
    }
    b1 = __builtin_bit_cast(half8, i1);
    b2 = __builtin_bit_cast(half8, i2);
}

// LDS: 2464 floats (9856 B) + 16384 f16 (32768 B) = 42624 B -> 3 blocks/CU.
#define LDS_BYTES 42624

// NOTE (measured R4/R5): __launch_bounds__ arg2 = min BLOCKS/CU on this
// toolchain. (512,3) -> 85-VGPR cap.
// Spill tripwire: hbm_bytes (clean ~5 MB; scratch-traffic ~1-2 GB).
// R8 measured 3 vs 4 blocks/CU perf-neutral (issue-bound) -> spend LDS on Cfi.
__global__ __launch_bounds__(512, 3) void sep_mfma(
    const float* __restrict__ coords,
    const float* __restrict__ x_params,
    const float* __restrict__ t_params,
    const float* __restrict__ xW1, const float* __restrict__ xb1,
    const float* __restrict__ xW2, const float* __restrict__ xb2,
    const float* __restrict__ tW1, const float* __restrict__ tb1,
    const float* __restrict__ tW2, const float* __restrict__ tb2,
    const float* __restrict__ h0,  const float* __restrict__ gh0,
    const float* __restrict__ f_Wh, const float* __restrict__ f_bh,
    const float* __restrict__ f_Wz, const float* __restrict__ f_bz,
    const float* __restrict__ g_Wh, const float* __restrict__ g_bh,
    const float* __restrict__ g_Wz, const float* __restrict__ g_bz,
    const float* __restrict__ d_W,  const float* __restrict__ d_b,
    float* __restrict__ out)
{
    extern __shared__ char smem[];
    float* sCfi   = (float*)smem;            // [8 waves][6][32] (Cf + ti*fz1)/2pi
    float* sfz0p  = sCfi + 1536;             // [6][32] fz0/2pi (permuted)
    float* sfz1p  = sfz0p + 192;             // [6][32] fz1/2pi (permuted)
    float* sCgp   = sfz1p + 192;             // [6][32] Cg/2pi (permuted, +gh0 fold at l=0)
    float* rawCfP = sCgp + 192;              // [6][32] Cf/2pi (permuted, +h0 fold at l=0)
    float* sdWp   = rawCfP + 192;            // [32] d_W (permuted, NOT scaled)
    float* shx    = sdWp + 32;
    float* sht    = shx + 32;
    float* sex    = sht + 32;
    float* set_   = sex + 32;
    // image: [f_Wh l=1..5 | g_Wh l=1..5 | g_Wz l=0..5] x [2 s-halves x 512] f16
    _Float16* sImg = (_Float16*)(set_ + 32);   // 16 slots * 1024 halves

    const int tid = threadIdx.x;
    const int b   = blockIdx.x >> 6;          // 64 blocks per batch
    const int ig  = (blockIdx.x >> 1) & 31;   // i-group: 8 i's per block
    const int jg  = blockIdx.x & 1;           // j-half: 4 tiles per block

    // ================= PROLOGUE =================
    // P1: encoder stage 1 + A-frag image build (f16 RNE, prescaled, 2-packed)
    if (tid < 32) {
        float a = xb1[tid];
        for (int k = 0; k < 16; ++k) a = fmaf(x_params[b * 16 + k], xW1[k * 32 + tid], a);
        shx[tid] = __sinf(a);
    } else if (tid < 64) {
        int d = tid - 32;
        float a = tb1[d];
        for (int k = 0; k < 8; ++k) a = fmaf(t_params[b * 8 + k], tW1[k * 32 + d], a);
        sht[d] = __sinf(a);
    }
    {
        int* sImgI = (int*)sImg;
        for (int ii = tid; ii < 8192; ii += 512) {
            int region = ii >> 9;             // slot index 0..15 (block-uniform)
            int r = ii & 511;
            int s = r >> 8, t = r & 255;
            int lane = t >> 2, jj2 = t & 3;
            int m = lane & 31, hg = lane >> 5;
            int c0 = 16*s + 8*(jj2 >> 1) + 4*hg + 2*(jj2 & 1);  // Pmap(s,hg,2*jj2)
            float w0, w1;
            if (region < 5)       { int l = region + 1;  w0 = f_Wh[(l*32 + c0)*32 + m]; w1 = f_Wh[(l*32 + c0 + 1)*32 + m]; }
            else if (region < 10) { int l = region - 4;  w0 = g_Wh[(l*32 + c0)*32 + m]; w1 = g_Wh[(l*32 + c0 + 1)*32 + m]; }
            else                  { int l = region - 10; w0 = g_Wz[(l*64 + c0)*32 + m]; w1 = g_Wz[(l*64 + c0 + 1)*32 + m]; }
            sImgI[ii] = __builtin_bit_cast(int,
                __builtin_amdgcn_cvt_pkrtz(w0 * INV2PI, w1 * INV2PI));
        }
    }
    __syncthreads();

    // P2: encoder stage 2 + prescaled fz0p/fz1p + dWp
    if (tid < 32) {
        float a = xb2[tid];
        for (int c = 0; c < 32; ++c) a = fmaf(shx[c], xW2[c * 32 + tid], a);
        sex[tid] = a;
    } else if (tid < 64) {
        int d = tid - 32;
        float a = tb2[d];
        for (int c = 0; c < 32; ++c) a = fmaf(sht[c], tW2[c * 32 + d], a);
        set_[d] = a;
    }
    if (tid < 192) {
        int l = tid >> 5, p = tid & 31, d = Qmap(p);
        sfz0p[tid] = f_Wz[(l * 34 + 0) * 32 + d] * INV2PI;
        sfz1p[tid] = f_Wz[(l * 34 + 1) * 32 + d] * INV2PI;
    }
    if (tid < 32) sdWp[tid] = d_W[Qmap(tid)];
    __syncthreads();

    // P3: Cf and Cg (permuted, prescaled; h0/gh0 matvecs folded into l=0)
    if (tid < 192) {
        int l = tid >> 5, p = tid & 31, d = Qmap(p);
        float a = f_bh[l * 32 + d] + f_bz[l * 32 + d];
        for (int c = 0; c < 32; ++c) a = fmaf(set_[c], f_Wz[(l * 34 + 2 + c) * 32 + d], a);
        if (l == 0)
            for (int c = 0; c < 32; ++c) a = fmaf(h0[c], f_Wh[c * 32 + d], a);
        rawCfP[tid] = a * INV2PI;
        float g = g_bh[l * 32 + d] + g_bz[l * 32 + d];
        for (int c = 0; c < 32; ++c) g = fmaf(sex[c], g_Wz[(l * 64 + 32 + c) * 32 + d], g);
        if (l == 0)
            for (int c = 0; c < 32; ++c) g = fmaf(gh0[c], g_Wh[c * 32 + d], g);
        sCgp[tid] = g * INV2PI;
    }
    __syncthreads();

    // P4: per-wave Cfi = rawCfP + ti*fz1p (both already prescaled)
    for (int idx = tid; idx < 1536; idx += 512) {
        int w = idx / 192, r2 = idx % 192;
        float ti = coords[(b * 256 + ig * 8 + w) * 2 + 1];
        sCfi[idx] = fmaf(ti, sfz1p[r2], rawCfP[r2]);
    }
    __syncthreads();

    // ================= MAIN =================
    const int lane = tid & 63, wave = tid >> 6;
    const int i = ig * 8 + wave;
    const int e = lane & 31, hk = lane >> 5;
    const int pb = hk * 16;
    const float db = d_b[0];
    const float* cfiW = &sCfi[wave * 192];

    #pragma unroll 1
    for (int t = 0; t < 4; ++t) {
        const int tile = jg * 4 + t;
        const int j = tile * 32 + e;
        const float xj = coords[(b * 256 + j) * 2];

        floatx16 acc;
        half8 hB1, hB2;

        // ---- f layer 0: h0 term folded into Cfi -> no MFMA ----
        {
            const float* cfi = cfiW + pb;
            const float* z0  = &sfz0p[pb];
            #pragma unroll
            for (int r = 0; r < 16; ++r) acc[r] = fmaf(xj, z0[r], cfi[r]);
            sincvt(acc, hB1, hB2);
        }
        // ---- f layers 1..5 ----
        for (int l = 1; l < NB; ++l) {
            const float* cfi = cfiW + l * 32 + pb;
            const float* z0  = &sfz0p[l * 32 + pb];
            #pragma unroll
            for (int r = 0; r < 16; ++r) acc[r] = fmaf(xj, z0[r], cfi[r]);
            const _Float16* base = &sImg[((l - 1) * 2) * 512 + lane * 8];
            half8 ah0 = *(const half8*)(base);
            half8 ah1 = *(const half8*)(base + 512);
            acc = MFMA(ah0, hB1, acc);
            acc = MFMA(ah1, hB2, acc);
            sincvt(acc, hB1, hB2);
        }

        // ---- g layer 0: gh0 term folded into Cg -> only Wz MFMAs ----
        half8 gB1, gB2;
        {
            const float* cg = &sCgp[pb];
            #pragma unroll
            for (int r = 0; r < 16; ++r) acc[r] = cg[r];
            const _Float16* bz = &sImg[10240 + lane * 8];
            half8 wz0 = *(const half8*)(bz);
            half8 wz1 = *(const half8*)(bz + 512);
            acc = MFMA(wz0, hB1, acc);
            acc = MFMA(wz1, hB2, acc);
            sincvt(acc, gB1, gB2);
        }
        // ---- g layers 1..5 ----
        for (int l = 1; l < NB; ++l) {
            const float* cg = &sCgp[l * 32 + pb];
            #pragma unroll
            for (int r = 0; r < 16; ++r) acc[r] = cg[r];
            const _Float16* bh = &sImg[5120 + ((l - 1) * 2) * 512 + lane * 8];
            const _Float16* bz = &sImg[10240 + (l * 2) * 512 + lane * 8];
            half8 wh0 = *(const half8*)(bh);
            half8 wh1 = *(const half8*)(bh + 512);
            half8 wz0 = *(const half8*)(bz);
            half8 wz1 = *(const half8*)(bz + 512);
            acc = MFMA(wh0, gB1, acc);
            acc = MFMA(wh1, gB2, acc);
            acc = MFMA(wz0, hB1, acc);
            acc = MFMA(wz1, hB2, acc);
            if (l < NB - 1) sincvt(acc, gB1, gB2);
        }

        // ---- decode ----
        float u = 0.0f;
        #pragma unroll
        for (int r = 0; r < 16; ++r) u = fmaf(__builtin_amdgcn_sinf(acc[r]), sdWp[pb + r], u);
        u += __shfl_xor(u, 32);
        if (hk == 0) out[(b * 256 + i) * 256 + j] = u + db;
    }
}

extern "C" void kernel_launch(void* const* d_in, const int* in_sizes, int n_in,
                              void* d_out, int out_size, void* d_ws, size_t ws_size,
                              hipStream_t stream) {
    const float* coords   = (const float*)d_in[0];
    const float* x_params = (const float*)d_in[1];
    const float* t_params = (const float*)d_in[2];
    const float* xW1 = (const float*)d_in[3];
    const float* xb1 = (const float*)d_in[4];
    const float* xW2 = (const float*)d_in[5];
    const float* xb2 = (const float*)d_in[6];
    const float* tW1 = (const float*)d_in[7];
    const float* tb1 = (const float*)d_in[8];
    const float* tW2 = (const float*)d_in[9];
    const float* tb2 = (const float*)d_in[10];
    const float* h0  = (const float*)d_in[11];
    const float* gh0 = (const float*)d_in[12];
    const float* f_Wh = (const float*)d_in[13];
    const float* f_bh = (const float*)d_in[14];
    const float* f_Wz = (const float*)d_in[15];
    const float* f_bz = (const float*)d_in[16];
    const float* g_Wh = (const float*)d_in[17];
    const float* g_bh = (const float*)d_in[18];
    const float* g_Wz = (const float*)d_in[19];
    const float* g_bz = (const float*)d_in[20];
    const float* d_W  = (const float*)d_in[21];
    const float* d_b  = (const float*)d_in[22];

    (void)hipFuncSetAttribute((const void*)sep_mfma,
                              hipFuncAttributeMaxDynamicSharedMemorySize, LDS_BYTES);

    // 16 batches * 32 i-groups * 2 j-halves = 1024 blocks of 512 threads
    sep_mfma<<<1024, 512, LDS_BYTES, stream>>>(
        coords, x_params, t_params, xW1, xb1, xW2, xb2, tW1, tb1, tW2, tb2,
        h0, gh0, f_Wh, f_bh, f_Wz, f_bz, g_Wh, g_bh, g_Wz, g_bz, d_W, d_b,
        (float*)d_out);
}

// Round 12
// 754.025 us; speedup vs baseline: 1.0107x; 1.0107x over previous
//
#include <hip/hip_runtime.h>

#define DIM 32
#define NB  6
#define INV2PI 0.15915494309189535f

typedef _Float16 half8  __attribute__((ext_vector_type(8)));
typedef int      int4v  __attribute__((ext_vector_type(4)));
typedef float    floatx16 __attribute__((ext_vector_type(16)));

// Reinterpret an integer-typed 4-VGPR tuple as the f16 MFMA operand type.
// Register-level no-op. NOTE (measured R10/R11): keeping half8-typed values
// live (or loading them from LDS as f16 vectors) causes ~2 GB scratch traffic
// at 84 VGPR; integer-typed registers (short8/int4v, R3-R8) allocate cleanly.
// So all storage is integer; bit_cast happens only at the MFMA call site.
#define ASH(x) __builtin_bit_cast(half8, x)

// B-frag slot (s,h,j) holds raw channel P; C/D reg (r,h) holds raw channel Q.
__device__ __forceinline__ int Qmap(int p) { int r = p & 15, h = p >> 4; return 8*(r>>2) + 4*h + (r&3); }

#define MFMA(a, b, c) __builtin_amdgcn_mfma_f32_32x32x16_f16((a), (b), (c), 0, 0, 0)

// acc in revolution domain (weights prescaled by 1/2pi):
// raw v_sin then pairwise f16 pack via v_cvt_pkrtz (2 acts / instr).
__device__ __forceinline__ void sincvt(const floatx16& acc, int4v& b1, int4v& b2) {
    #pragma unroll
    for (int q = 0; q < 4; ++q) {
        b1[q] = __builtin_bit_cast(int,
                    __builtin_amdgcn_cvt_pkrtz(__builtin_amdgcn_sinf(acc[2*q]),
                                               __builtin_amdgcn_sinf(acc[2*q+1])));
        b2[q] = __builtin_bit_cast(int,
                    __builtin_amdgcn_cvt_pkrtz(__builtin_amdgcn_sinf(acc[8+2*q]),
                                               __builtin_amdgcn_sinf(acc[8+2*q+1])));
    }
}

// LDS: 2464 floats (9856 B) + 16384 f16 (32768 B) = 42624 B -> 3 blocks/CU.
#define LDS_BYTES 42624

// NOTE (measured R4/R5): __launch_bounds__ arg2 = min BLOCKS/CU on this
// toolchain. (512,3) -> 85-VGPR cap.
// Spill tripwire: hbm_bytes (clean ~5 MB; scratch-traffic ~1-2 GB).
__global__ __launch_bounds__(512, 3) void sep_mfma(
    const float* __restrict__ coords,
    const float* __restrict__ x_params,
    const float* __restrict__ t_params,
    const float* __restrict__ xW1, const float* __restrict__ xb1,
    const float* __restrict__ xW2, const float* __restrict__ xb2,
    const float* __restrict__ tW1, const float* __restrict__ tb1,
    const float* __restrict__ tW2, const float* __restrict__ tb2,
    const float* __restrict__ h0,  const float* __restrict__ gh0,
    const float* __restrict__ f_Wh, const float* __restrict__ f_bh,
    const float* __restrict__ f_Wz, const float* __restrict__ f_bz,
    const float* __restrict__ g_Wh, const float* __restrict__ g_bh,
    const float* __restrict__ g_Wz, const float* __restrict__ g_bz,
    const float* __restrict__ d_W,  const float* __restrict__ d_b,
    float* __restrict__ out)
{
    extern __shared__ char smem[];
    float* sCfi   = (float*)smem;            // [8 waves][6][32] (Cf + ti*fz1)/2pi
    float* sfz0p  = sCfi + 1536;             // [6][32] fz0/2pi (permuted)
    float* sfz1p  = sfz0p + 192;             // [6][32] fz1/2pi (permuted)
    float* sCgp   = sfz1p + 192;             // [6][32] Cg/2pi (permuted, +gh0 fold at l=0)
    float* rawCfP = sCgp + 192;              // [6][32] Cf/2pi (permuted, +h0 fold at l=0)
    float* sdWp   = rawCfP + 192;            // [32] d_W (permuted, NOT scaled)
    float* shx    = sdWp + 32;
    float* sht    = shx + 32;
    float* sex    = sht + 32;
    float* set_   = sex + 32;
    // image: [f_Wh l=1..5 | g_Wh l=1..5 | g_Wz l=0..5] x [2 s-halves x 512]
    // f16 bit patterns stored in integer-typed LDS.
    unsigned short* sImg = (unsigned short*)(set_ + 32);   // 16 slots * 1024

    const int tid = threadIdx.x;
    const int b   = blockIdx.x >> 6;          // 64 blocks per batch
    const int ig  = (blockIdx.x >> 1) & 31;   // i-group: 8 i's per block
    const int jg  = blockIdx.x & 1;           // j-half: 4 tiles per block

    // ================= PROLOGUE =================
    // P1: encoder stage 1 + A-frag image build (f16 via pkrtz, prescaled, 2-packed)
    if (tid < 32) {
        float a = xb1[tid];
        for (int k = 0; k < 16; ++k) a = fmaf(x_params[b * 16 + k], xW1[k * 32 + tid], a);
        shx[tid] = __sinf(a);
    } else if (tid < 64) {
        int d = tid - 32;
        float a = tb1[d];
        for (int k = 0; k < 8; ++k) a = fmaf(t_params[b * 8 + k], tW1[k * 32 + d], a);
        sht[d] = __sinf(a);
    }
    {
        int* sImgI = (int*)sImg;
        for (int ii = tid; ii < 8192; ii += 512) {
            int region = ii >> 9;             // slot index 0..15 (block-uniform)
            int r = ii & 511;
            int s = r >> 8, t = r & 255;
            int lane = t >> 2, jj2 = t & 3;
            int m = lane & 31, hg = lane >> 5;
            int c0 = 16*s + 8*(jj2 >> 1) + 4*hg + 2*(jj2 & 1);  // Pmap(s,hg,2*jj2)
            float w0, w1;
            if (region < 5)       { int l = region + 1;  w0 = f_Wh[(l*32 + c0)*32 + m]; w1 = f_Wh[(l*32 + c0 + 1)*32 + m]; }
            else if (region < 10) { int l = region - 4;  w0 = g_Wh[(l*32 + c0)*32 + m]; w1 = g_Wh[(l*32 + c0 + 1)*32 + m]; }
            else                  { int l = region - 10; w0 = g_Wz[(l*64 + c0)*32 + m]; w1 = g_Wz[(l*64 + c0 + 1)*32 + m]; }
            sImgI[ii] = __builtin_bit_cast(int,
                __builtin_amdgcn_cvt_pkrtz(w0 * INV2PI, w1 * INV2PI));
        }
    }
    __syncthreads();

    // P2: encoder stage 2 + prescaled fz0p/fz1p + dWp
    if (tid < 32) {
        float a = xb2[tid];
        for (int c = 0; c < 32; ++c) a = fmaf(shx[c], xW2[c * 32 + tid], a);
        sex[tid] = a;
    } else if (tid < 64) {
        int d = tid - 32;
        float a = tb2[d];
        for (int c = 0; c < 32; ++c) a = fmaf(sht[c], tW2[c * 32 + d], a);
        set_[d] = a;
    }
    if (tid < 192) {
        int l = tid >> 5, p = tid & 31, d = Qmap(p);
        sfz0p[tid] = f_Wz[(l * 34 + 0) * 32 + d] * INV2PI;
        sfz1p[tid] = f_Wz[(l * 34 + 1) * 32 + d] * INV2PI;
    }
    if (tid < 32) sdWp[tid] = d_W[Qmap(tid)];
    __syncthreads();

    // P3: Cf and Cg (permuted, prescaled; h0/gh0 matvecs folded into l=0)
    if (tid < 192) {
        int l = tid >> 5, p = tid & 31, d = Qmap(p);
        float a = f_bh[l * 32 + d] + f_bz[l * 32 + d];
        for (int c = 0; c < 32; ++c) a = fmaf(set_[c], f_Wz[(l * 34 + 2 + c) * 32 + d], a);
        if (l == 0)
            for (int c = 0; c < 32; ++c) a = fmaf(h0[c], f_Wh[c * 32 + d], a);
        rawCfP[tid] = a * INV2PI;
        float g = g_bh[l * 32 + d] + g_bz[l * 32 + d];
        for (int c = 0; c < 32; ++c) g = fmaf(sex[c], g_Wz[(l * 64 + 32 + c) * 32 + d], g);
        if (l == 0)
            for (int c = 0; c < 32; ++c) g = fmaf(gh0[c], g_Wh[c * 32 + d], g);
        sCgp[tid] = g * INV2PI;
    }
    __syncthreads();

    // P4: per-wave Cfi = rawCfP + ti*fz1p (both already prescaled)
    for (int idx = tid; idx < 1536; idx += 512) {
        int w = idx / 192, r2 = idx % 192;
        float ti = coords[(b * 256 + ig * 8 + w) * 2 + 1];
        sCfi[idx] = fmaf(ti, sfz1p[r2], rawCfP[r2]);
    }
    __syncthreads();

    // ================= MAIN =================
    const int lane = tid & 63, wave = tid >> 6;
    const int i = ig * 8 + wave;
    const int e = lane & 31, hk = lane >> 5;
    const int pb = hk * 16;
    const float db = d_b[0];
    const float* cfiW = &sCfi[wave * 192];

    #pragma unroll 1
    for (int t = 0; t < 4; ++t) {
        const int tile = jg * 4 + t;
        const int j = tile * 32 + e;
        const float xj = coords[(b * 256 + j) * 2];

        floatx16 acc;
        int4v hB1, hB2;

        // ---- f layer 0: h0 term folded into Cfi -> no MFMA ----
        {
            const float* cfi = cfiW + pb;
            const float* z0  = &sfz0p[pb];
            #pragma unroll
            for (int r = 0; r < 16; ++r) acc[r] = fmaf(xj, z0[r], cfi[r]);
            sincvt(acc, hB1, hB2);
        }
        // ---- f layers 1..5 ----
        for (int l = 1; l < NB; ++l) {
            const float* cfi = cfiW + l * 32 + pb;
            const float* z0  = &sfz0p[l * 32 + pb];
            #pragma unroll
            for (int r = 0; r < 16; ++r) acc[r] = fmaf(xj, z0[r], cfi[r]);
            const unsigned short* base = &sImg[((l - 1) * 2) * 512 + lane * 8];
            int4v ah0 = *(const int4v*)(base);
            int4v ah1 = *(const int4v*)(base + 512);
            acc = MFMA(ASH(ah0), ASH(hB1), acc);
            acc = MFMA(ASH(ah1), ASH(hB2), acc);
            sincvt(acc, hB1, hB2);
        }

        // ---- g layer 0: gh0 term folded into Cg -> only Wz MFMAs ----
        int4v gB1, gB2;
        {
            const float* cg = &sCgp[pb];
            #pragma unroll
            for (int r = 0; r < 16; ++r) acc[r] = cg[r];
            const unsigned short* bz = &sImg[10240 + lane * 8];
            int4v wz0 = *(const int4v*)(bz);
            int4v wz1 = *(const int4v*)(bz + 512);
            acc = MFMA(ASH(wz0), ASH(hB1), acc);
            acc = MFMA(ASH(wz1), ASH(hB2), acc);
            sincvt(acc, gB1, gB2);
        }
        // ---- g layers 1..5 ----
        for (int l = 1; l < NB; ++l) {
            const float* cg = &sCgp[l * 32 + pb];
            #pragma unroll
            for (int r = 0; r < 16; ++r) acc[r] = cg[r];
            const unsigned short* bh = &sImg[5120 + ((l - 1) * 2) * 512 + lane * 8];
            const unsigned short* bz = &sImg[10240 + (l * 2) * 512 + lane * 8];
            int4v wh0 = *(const int4v*)(bh);
            int4v wh1 = *(const int4v*)(bh + 512);
            int4v wz0 = *(const int4v*)(bz);
            int4v wz1 = *(const int4v*)(bz + 512);
            acc = MFMA(ASH(wh0), ASH(gB1), acc);
            acc = MFMA(ASH(wh1), ASH(gB2), acc);
            acc = MFMA(ASH(wz0), ASH(hB1), acc);
            acc = MFMA(ASH(wz1), ASH(hB2), acc);
            if (l < NB - 1) sincvt(acc, gB1, gB2);
        }

        // ---- decode ----
        float u = 0.0f;
        #pragma unroll
        for (int r = 0; r < 16; ++r) u = fmaf(__builtin_amdgcn_sinf(acc[r]), sdWp[pb + r], u);
        u += __shfl_xor(u, 32);
        if (hk == 0) out[(b * 256 + i) * 256 + j] = u + db;
    }
}

extern "C" void kernel_launch(void* const* d_in, const int* in_sizes, int n_in,
                              void* d_out, int out_size, void* d_ws, size_t ws_size,
                              hipStream_t stream) {
    const float* coords   = (const float*)d_in[0];
    const float* x_params = (const float*)d_in[1];
    const float* t_params = (const float*)d_in[2];
    const float* xW1 = (const float*)d_in[3];
    const float* xb1 = (const float*)d_in[4];
    const float* xW2 = (const float*)d_in[5];
    const float* xb2 = (const float*)d_in[6];
    const float* tW1 = (const float*)d_in[7];
    const float* tb1 = (const float*)d_in[8];
    const float* tW2 = (const float*)d_in[9];
    const float* tb2 = (const float*)d_in[10];
    const float* h0  = (const float*)d_in[11];
    const float* gh0 = (const float*)d_in[12];
    const float* f_Wh = (const float*)d_in[13];
    const float* f_bh = (const float*)d_in[14];
    const float* f_Wz = (const float*)d_in[15];
    const float* f_bz = (const float*)d_in[16];
    const float* g_Wh = (const float*)d_in[17];
    const float* g_bh = (const float*)d_in[18];
    const float* g_Wz = (const float*)d_in[19];
    const float* g_bz = (const float*)d_in[20];
    const float* d_W  = (const float*)d_in[21];
    const float* d_b  = (const float*)d_in[22];

    (void)hipFuncSetAttribute((const void*)sep_mfma,
                              hipFuncAttributeMaxDynamicSharedMemorySize, LDS_BYTES);

    // 16 batches * 32 i-groups * 2 j-halves = 1024 blocks of 512 threads
    sep_mfma<<<1024, 512, LDS_BYTES, stream>>>(
        coords, x_params, t_params, xW1, xb1, xW2, xb2, tW1, tb1, tW2, tb2,
        h0, gh0, f_Wh, f_bh, f_Wz, f_bz, g_Wh, g_bh, g_Wz, g_bz, d_W, d_b,
        (float*)d_out);
}

// Round 13
// 750.385 us; speedup vs baseline: 1.0156x; 1.0049x over previous
//
#include <hip/hip_runtime.h>

#define DIM 32
#define NB  6
#define INV2PI 0.15915494309189535f

typedef short short8   __attribute__((ext_vector_type(8)));
typedef int   int4v    __attribute__((ext_vector_type(4)));
typedef float floatx16 __attribute__((ext_vector_type(16)));

__device__ __forceinline__ unsigned short f2bf(float f) {   // RNE
    unsigned u = __float_as_uint(f);
    return (unsigned short)((u + 0x7FFF + ((u >> 16) & 1)) >> 16);
}
// B-frag slot (s,h,j) holds raw channel P; C/D reg (r,h) holds raw channel Q.
__device__ __forceinline__ int Qmap(int p) { int r = p & 15, h = p >> 4; return 8*(r>>2) + 4*h + (r&3); }

// NOTE (measured R9-R12): ANY f16 vector types (v8f16 MFMA operands, f16x2
// cvt_pkrtz results) trigger ~2 GB scratch traffic at 84 VGPR on this
// backend, immune to union/bit_cast/int-storage workarounds. bf16 MFMA with
// short8 operands allocates cleanly (R3-R8). Stay bf16-only.
#define MFMA(a, b, c) __builtin_amdgcn_mfma_f32_32x32x16_bf16((a), (b), (c), 0, 0, 0)

// acc in revolution domain (weights prescaled by 1/2pi): raw v_sin, then
// single bf16 act via round-half-up (+0x8000) and v_perm pairwise pack.
// (Half-up == RNE except at exact ties; symmetric, unbiased.)
__device__ __forceinline__ void sincvt(const floatx16& acc, short8& b1, short8& b2) {
    int4v i1, i2;
    #pragma unroll
    for (int q = 0; q < 4; ++q) {
        unsigned a0 = __float_as_uint(__builtin_amdgcn_sinf(acc[2*q]))     + 0x8000u;
        unsigned a1 = __float_as_uint(__builtin_amdgcn_sinf(acc[2*q+1]))   + 0x8000u;
        i1[q] = (int)__builtin_amdgcn_perm(a1, a0, 0x07060302u);
        unsigned c0 = __float_as_uint(__builtin_amdgcn_sinf(acc[8+2*q]))   + 0x8000u;
        unsigned c1 = __float_as_uint(__builtin_amdgcn_sinf(acc[8+2*q+1])) + 0x8000u;
        i2[q] = (int)__builtin_amdgcn_perm(c1, c0, 0x07060302u);
    }
    b1 = __builtin_bit_cast(short8, i1);
    b2 = __builtin_bit_cast(short8, i2);
}

// LDS: 2464 floats (9856 B) + 16384 shorts (32768 B) = 42624 B -> 3 blocks/CU.
#define LDS_BYTES 42624

// NOTE (measured R4/R5): __launch_bounds__ arg2 = min BLOCKS/CU on this
// toolchain. (512,3) -> 85-VGPR cap. Spill tripwire: hbm_bytes.
// R8: 3 vs 4 blocks/CU perf-neutral (issue-bound) -> spend LDS on Cfi.
__global__ __launch_bounds__(512, 3) void sep_mfma(
    const float* __restrict__ coords,
    const float* __restrict__ x_params,
    const float* __restrict__ t_params,
    const float* __restrict__ xW1, const float* __restrict__ xb1,
    const float* __restrict__ xW2, const float* __restrict__ xb2,
    const float* __restrict__ tW1, const float* __restrict__ tb1,
    const float* __restrict__ tW2, const float* __restrict__ tb2,
    const float* __restrict__ h0,  const float* __restrict__ gh0,
    const float* __restrict__ f_Wh, const float* __restrict__ f_bh,
    const float* __restrict__ f_Wz, const float* __restrict__ f_bz,
    const float* __restrict__ g_Wh, const float* __restrict__ g_bh,
    const float* __restrict__ g_Wz, const float* __restrict__ g_bz,
    const float* __restrict__ d_W,  const float* __restrict__ d_b,
    float* __restrict__ out)
{
    extern __shared__ char smem[];
    float* sCfi   = (float*)smem;            // [8 waves][6][32] (Cf + ti*fz1)/2pi
    float* sfz0p  = sCfi + 1536;             // [6][32] fz0/2pi (permuted)
    float* sfz1p  = sfz0p + 192;             // [6][32] fz1/2pi (permuted)
    float* sCgp   = sfz1p + 192;             // [6][32] Cg/2pi (permuted, +gh0 fold at l=0)
    float* rawCfP = sCgp + 192;              // [6][32] Cf/2pi (permuted, +h0 fold at l=0)
    float* sdWp   = rawCfP + 192;            // [32] d_W (permuted, NOT scaled)
    float* shx    = sdWp + 32;
    float* sht    = shx + 32;
    float* sex    = sht + 32;
    float* set_   = sex + 32;
    // image: [f_Wh l=1..5 | g_Wh l=1..5 | g_Wz l=0..5] x [2 s-halves x 512] bf16
    unsigned short* sImg = (unsigned short*)(set_ + 32);   // 16 regions * 1024

    const int tid = threadIdx.x;
    const int b   = blockIdx.x >> 6;          // 64 blocks per batch
    const int ig  = (blockIdx.x >> 1) & 31;   // i-group: 8 i's per block
    const int jg  = blockIdx.x & 1;           // j-half: 4 tiles per block

    // ================= PROLOGUE =================
    // P1: encoder stage 1 + A-frag image build (bf16 RNE, prescaled, 2-packed)
    if (tid < 32) {
        float a = xb1[tid];
        for (int k = 0; k < 16; ++k) a = fmaf(x_params[b * 16 + k], xW1[k * 32 + tid], a);
        shx[tid] = __sinf(a);
    } else if (tid < 64) {
        int d = tid - 32;
        float a = tb1[d];
        for (int k = 0; k < 8; ++k) a = fmaf(t_params[b * 8 + k], tW1[k * 32 + d], a);
        sht[d] = __sinf(a);
    }
    {
        int* sImgI = (int*)sImg;
        for (int ii = tid; ii < 8192; ii += 512) {
            int region = ii >> 9;             // region 0..15 (block-uniform)
            int r = ii & 511;
            int s = r >> 8, t = r & 255;
            int lane = t >> 2, jj2 = t & 3;
            int m = lane & 31, hg = lane >> 5;
            int c0 = 16*s + 8*(jj2 >> 1) + 4*hg + 2*(jj2 & 1);  // Pmap(s,hg,2*jj2)
            float w0, w1;
            if (region < 5)       { int l = region + 1;  w0 = f_Wh[(l*32 + c0)*32 + m]; w1 = f_Wh[(l*32 + c0 + 1)*32 + m]; }
            else if (region < 10) { int l = region - 4;  w0 = g_Wh[(l*32 + c0)*32 + m]; w1 = g_Wh[(l*32 + c0 + 1)*32 + m]; }
            else                  { int l = region - 10; w0 = g_Wz[(l*64 + c0)*32 + m]; w1 = g_Wz[(l*64 + c0 + 1)*32 + m]; }
            unsigned p0 = f2bf(w0 * INV2PI), p1 = f2bf(w1 * INV2PI);
            sImgI[ii] = (int)(p0 | (p1 << 16));
        }
    }
    __syncthreads();

    // P2: encoder stage 2 + prescaled fz0p/fz1p + dWp
    if (tid < 32) {
        float a = xb2[tid];
        for (int c = 0; c < 32; ++c) a = fmaf(shx[c], xW2[c * 32 + tid], a);
        sex[tid] = a;
    } else if (tid < 64) {
        int d = tid - 32;
        float a = tb2[d];
        for (int c = 0; c < 32; ++c) a = fmaf(sht[c], tW2[c * 32 + d], a);
        set_[d] = a;
    }
    if (tid < 192) {
        int l = tid >> 5, p = tid & 31, d = Qmap(p);
        sfz0p[tid] = f_Wz[(l * 34 + 0) * 32 + d] * INV2PI;
        sfz1p[tid] = f_Wz[(l * 34 + 1) * 32 + d] * INV2PI;
    }
    if (tid < 32) sdWp[tid] = d_W[Qmap(tid)];
    __syncthreads();

    // P3: Cf and Cg (permuted, prescaled; h0/gh0 matvecs folded into l=0)
    if (tid < 192) {
        int l = tid >> 5, p = tid & 31, d = Qmap(p);
        float a = f_bh[l * 32 + d] + f_bz[l * 32 + d];
        for (int c = 0; c < 32; ++c) a = fmaf(set_[c], f_Wz[(l * 34 + 2 + c) * 32 + d], a);
        if (l == 0)
            for (int c = 0; c < 32; ++c) a = fmaf(h0[c], f_Wh[c * 32 + d], a);
        rawCfP[tid] = a * INV2PI;
        float g = g_bh[l * 32 + d] + g_bz[l * 32 + d];
        for (int c = 0; c < 32; ++c) g = fmaf(sex[c], g_Wz[(l * 64 + 32 + c) * 32 + d], g);
        if (l == 0)
            for (int c = 0; c < 32; ++c) g = fmaf(gh0[c], g_Wh[c * 32 + d], g);
        sCgp[tid] = g * INV2PI;
    }
    __syncthreads();

    // P4: per-wave Cfi = rawCfP + ti*fz1p (both already prescaled)
    for (int idx = tid; idx < 1536; idx += 512) {
        int w = idx / 192, r2 = idx % 192;
        float ti = coords[(b * 256 + ig * 8 + w) * 2 + 1];
        sCfi[idx] = fmaf(ti, sfz1p[r2], rawCfP[r2]);
    }
    __syncthreads();

    // ================= MAIN =================
    const int lane = tid & 63, wave = tid >> 6;
    const int i = ig * 8 + wave;
    const int e = lane & 31, hk = lane >> 5;
    const int pb = hk * 16;
    const float db = d_b[0];
    const float* cfiW = &sCfi[wave * 192];

    #pragma unroll 1
    for (int t = 0; t < 4; ++t) {
        const int tile = jg * 4 + t;
        const int j = tile * 32 + e;
        const float xj = coords[(b * 256 + j) * 2];

        floatx16 acc;
        short8 hB1, hB2;

        // ---- f layer 0: h0 term folded into Cfi -> no MFMA ----
        {
            const float* cfi = cfiW + pb;
            const float* z0  = &sfz0p[pb];
            #pragma unroll
            for (int r = 0; r < 16; ++r) acc[r] = fmaf(xj, z0[r], cfi[r]);
            sincvt(acc, hB1, hB2);
        }
        // ---- f layers 1..5 ----
        for (int l = 1; l < NB; ++l) {
            const float* cfi = cfiW + l * 32 + pb;
            const float* z0  = &sfz0p[l * 32 + pb];
            #pragma unroll
            for (int r = 0; r < 16; ++r) acc[r] = fmaf(xj, z0[r], cfi[r]);
            const unsigned short* base = &sImg[((l - 1) * 2) * 512 + lane * 8];
            short8 ah0 = *(const short8*)(base);
            short8 ah1 = *(const short8*)(base + 512);
            acc = MFMA(ah0, hB1, acc);
            acc = MFMA(ah1, hB2, acc);
            sincvt(acc, hB1, hB2);
        }

        // ---- g layer 0: gh0 term folded into Cg -> only Wz MFMAs ----
        short8 gB1, gB2;
        {
            const float* cg = &sCgp[pb];
            #pragma unroll
            for (int r = 0; r < 16; ++r) acc[r] = cg[r];
            const unsigned short* bz = &sImg[10240 + lane * 8];
            short8 wz0 = *(const short8*)(bz);
            short8 wz1 = *(const short8*)(bz + 512);
            acc = MFMA(wz0, hB1, acc);
            acc = MFMA(wz1, hB2, acc);
            sincvt(acc, gB1, gB2);
        }
        // ---- g layers 1..5 ----
        for (int l = 1; l < NB; ++l) {
            const float* cg = &sCgp[l * 32 + pb];
            #pragma unroll
            for (int r = 0; r < 16; ++r) acc[r] = cg[r];
            const unsigned short* bh = &sImg[5120 + ((l - 1) * 2) * 512 + lane * 8];
            const unsigned short* bz = &sImg[10240 + (l * 2) * 512 + lane * 8];
            short8 wh0 = *(const short8*)(bh);
            short8 wh1 = *(const short8*)(bh + 512);
            short8 wz0 = *(const short8*)(bz);
            short8 wz1 = *(const short8*)(bz + 512);
            acc = MFMA(wh0, gB1, acc);
            acc = MFMA(wh1, gB2, acc);
            acc = MFMA(wz0, hB1, acc);
            acc = MFMA(wz1, hB2, acc);
            if (l < NB - 1) sincvt(acc, gB1, gB2);
        }

        // ---- decode ----
        float u = 0.0f;
        #pragma unroll
        for (int r = 0; r < 16; ++r) u = fmaf(__builtin_amdgcn_sinf(acc[r]), sdWp[pb + r], u);
        u += __shfl_xor(u, 32);
        if (hk == 0) out[(b * 256 + i) * 256 + j] = u + db;
    }
}

extern "C" void kernel_launch(void* const* d_in, const int* in_sizes, int n_in,
                              void* d_out, int out_size, void* d_ws, size_t ws_size,
                              hipStream_t stream) {
    const float* coords   = (const float*)d_in[0];
    const float* x_params = (const float*)d_in[1];
    const float* t_params = (const float*)d_in[2];
    const float* xW1 = (const float*)d_in[3];
    const float* xb1 = (const float*)d_in[4];
    const float* xW2 = (const float*)d_in[5];
    const float* xb2 = (const float*)d_in[6];
    const float* tW1 = (const float*)d_in[7];
    const float* tb1 = (const float*)d_in[8];
    const float* tW2 = (const float*)d_in[9];
    const float* tb2 = (const float*)d_in[10];
    const float* h0  = (const float*)d_in[11];
    const float* gh0 = (const float*)d_in[12];
    const float* f_Wh = (const float*)d_in[13];
    const float* f_bh = (const float*)d_in[14];
    const float* f_Wz = (const float*)d_in[15];
    const float* f_bz = (const float*)d_in[16];
    const float* g_Wh = (const float*)d_in[17];
    const float* g_bh = (const float*)d_in[18];
    const float* g_Wz = (const float*)d_in[19];
    const float* g_bz = (const float*)d_in[20];
    const float* d_W  = (const float*)d_in[21];
    const float* d_b  = (const float*)d_in[22];

    (void)hipFuncSetAttribute((const void*)sep_mfma,
                              hipFuncAttributeMaxDynamicSharedMemorySize, LDS_BYTES);

    // 16 batches * 32 i-groups * 2 j-halves = 1024 blocks of 512 threads
    sep_mfma<<<1024, 512, LDS_BYTES, stream>>>(
        coords, x_params, t_params, xW1, xb1, xW2, xb2, tW1, tb1, tW2, tb2,
        h0, gh0, f_Wh, f_bh, f_Wz, f_bz, g_Wh, g_bh, g_Wz, g_bz, d_W, d_b,
        (float*)d_out);
}